// Round 10
// baseline (470.687 us; speedup 1.0000x reference)
//
#include <hip/hip_runtime.h>
#include <hip/hip_bf16.h>

#define N_NODE   100000
#define N_EDGE   1600000
#define IN_DIM   128
#define HID1     64
#define HID2     64
#define OUT_DIM  32
#define NUM_GRAPHS 256

#define NBUCK    782            // ceil(100000/128) node buckets of 128
#define BBLK     500            // binning blocks
#define EPB      3200           // edges per binning block (500*3200 = 1.6M exact)
#define STAGE_CAP 4096          // LDS staging capacity in k_local

typedef unsigned int uint;
typedef unsigned char uchar;
typedef unsigned short ushort_t;
typedef short bf16x8 __attribute__((ext_vector_type(8)));
typedef float f32x4 __attribute__((ext_vector_type(4)));

__device__ __forceinline__ float bflo(uint p) { return __uint_as_float(p << 16); }
__device__ __forceinline__ float bfhi(uint p) { return __uint_as_float(p & 0xFFFF0000u); }
__device__ __forceinline__ uint bfpack(float a, float b) {
    uint ua = __float_as_uint(a), ub = __float_as_uint(b);
    ua = (ua + 0x7FFFu + ((ua >> 16) & 1u)) >> 16;
    ub = (ub + 0x7FFFu + ((ub >> 16) & 1u)) & 0xFFFF0000u;
    return ua | ub;
}
__device__ __forceinline__ ushort_t bf16r(float f) {
    uint ua = __float_as_uint(f);
    return (ushort_t)((ua + 0x7FFFu + ((ua >> 16) & 1u)) >> 16);
}

// ---------------- preprocessing: binned CSR build (zero global atomics) ----------------

__global__ __launch_bounds__(256)
void k_count(const int2* __restrict__ snd2, const int2* __restrict__ rcv2,
             int* __restrict__ cntRA, int* __restrict__ cntSA) {
    __shared__ int cntR[NBUCK];
    __shared__ int cntS[NBUCK];
    const int t = threadIdx.x, blk = blockIdx.x;
    for (int i = t; i < NBUCK; i += 256) { cntR[i] = 0; cntS[i] = 0; }
    __syncthreads();
    const int base2 = blk * (EPB / 2);
    for (int i = 0; i < 7; ++i) {
        int local2 = i * 256 + t;
        if (local2 < EPB / 2) {
            int2 r = rcv2[base2 + local2];
            int2 s = snd2[base2 + local2];
            atomicAdd(&cntR[r.x >> 7], 1);
            atomicAdd(&cntR[r.y >> 7], 1);
            atomicAdd(&cntS[s.x >> 7], 1);
            atomicAdd(&cntS[s.y >> 7], 1);
        }
    }
    __syncthreads();
    for (int i = t; i < NBUCK; i += 256) {
        cntRA[blk * NBUCK + i] = cntR[i];
        cntSA[blk * NBUCK + i] = cntS[i];
    }
}

__global__ __launch_bounds__(256)
void k_scanb(int* __restrict__ cntRA, int* __restrict__ cntSA,
             int* __restrict__ rTotal, int* __restrict__ sTotal) {
    const int which = blockIdx.x / NBUCK;
    const int b = blockIdx.x % NBUCK;
    int* cntA = which ? cntSA : cntRA;
    int* total = which ? sTotal : rTotal;
    const int t = threadIdx.x, lane = t & 63, wave = t >> 6;
    __shared__ int sW[4];
    int carry = 0;
    for (int k = 0; k < 2; ++k) {
        int idx = k * 256 + t;
        int v = (idx < BBLK) ? cntA[idx * NBUCK + b] : 0;
        int inc = v;
        #pragma unroll
        for (int o = 1; o < 64; o <<= 1) { int n = __shfl_up(inc, o); if (lane >= o) inc += n; }
        if (lane == 63) sW[wave] = inc;
        __syncthreads();
        int wOff = 0;
        for (int w = 0; w < wave; ++w) wOff += sW[w];
        int tot = sW[0] + sW[1] + sW[2] + sW[3];
        int excl = carry + wOff + inc - v;
        if (idx < BBLK) cntA[idx * NBUCK + b] = excl;
        carry += tot;
        __syncthreads();
    }
    if (t == 0) total[b] = carry;
}

__global__ __launch_bounds__(256)
void k_scanB(const int* __restrict__ rTotal, const int* __restrict__ sTotal,
             int* __restrict__ rBase, int* __restrict__ sBase) {
    const int* total = blockIdx.x ? sTotal : rTotal;
    int* base = blockIdx.x ? sBase : rBase;
    const int t = threadIdx.x, lane = t & 63, wave = t >> 6;
    __shared__ int sW[4];
    int carry = 0;
    for (int k = 0; k < 4; ++k) {
        int idx = k * 256 + t;
        int v = (idx < NBUCK) ? total[idx] : 0;
        int inc = v;
        #pragma unroll
        for (int o = 1; o < 64; o <<= 1) { int n = __shfl_up(inc, o); if (lane >= o) inc += n; }
        if (lane == 63) sW[wave] = inc;
        __syncthreads();
        int wOff = 0;
        for (int w = 0; w < wave; ++w) wOff += sW[w];
        int tot = sW[0] + sW[1] + sW[2] + sW[3];
        int excl = carry + wOff + inc - v;
        if (idx < NBUCK) base[idx] = excl;
        carry += tot;
        __syncthreads();
    }
    if (t == 0) base[NBUCK] = carry;
}

__global__ __launch_bounds__(256)
void k_place(const int2* __restrict__ snd2, const int2* __restrict__ rcv2,
             const int* __restrict__ rColOff, const int* __restrict__ sColOff,
             const int* __restrict__ rBase, const int* __restrict__ sBase,
             uint* __restrict__ binned, uchar* __restrict__ sBin) {
    __shared__ int curR[NBUCK];
    __shared__ int curS[NBUCK];
    const int t = threadIdx.x, blk = blockIdx.x;
    for (int i = t; i < NBUCK; i += 256) { curR[i] = 0; curS[i] = 0; }
    __syncthreads();
    const int base2 = blk * (EPB / 2);
    for (int i = 0; i < 7; ++i) {
        int local2 = i * 256 + t;
        if (local2 < EPB / 2) {
            int2 r = rcv2[base2 + local2];
            int2 s = snd2[base2 + local2];
            int b0 = r.x >> 7, b1 = r.y >> 7;
            int l0 = atomicAdd(&curR[b0], 1);
            binned[rBase[b0] + rColOff[blk * NBUCK + b0] + l0] = ((uint)s.x << 7) | (uint)(r.x & 127);
            int l1 = atomicAdd(&curR[b1], 1);
            binned[rBase[b1] + rColOff[blk * NBUCK + b1] + l1] = ((uint)s.y << 7) | (uint)(r.y & 127);
            int c0 = s.x >> 7, c1 = s.y >> 7;
            int m0 = atomicAdd(&curS[c0], 1);
            sBin[sBase[c0] + sColOff[blk * NBUCK + c0] + m0] = (uchar)(s.x & 127);
            int m1 = atomicAdd(&curS[c1], 1);
            sBin[sBase[c1] + sColOff[blk * NBUCK + c1] + m1] = (uchar)(s.y & 127);
        }
    }
}

__global__ __launch_bounds__(256)
void k_local(const uint* __restrict__ binned, const uchar* __restrict__ sBin,
             const int* __restrict__ rBase, const int* __restrict__ sBase,
             int* __restrict__ rowptr, float* __restrict__ normS, float* __restrict__ normR,
             int* __restrict__ sortedSrc) {
    __shared__ uint staged[STAGE_CAP];
    __shared__ int cnt[128], excl[128], cur[128], cntS2[128];
    const int b = blockIdx.x, t = threadIdx.x;
    const int e0 = rBase[b], e1 = rBase[b + 1], m = e1 - e0;
    const int s0 = sBase[b], s1 = sBase[b + 1], ms = s1 - s0;
    if (t < 128) { cnt[t] = 0; cur[t] = 0; cntS2[t] = 0; }
    __syncthreads();
    for (int i = t; i < m; i += 256) {
        uint v = binned[e0 + i];
        if (i < STAGE_CAP) staged[i] = v;
        atomicAdd(&cnt[v & 127u], 1);
    }
    for (int i = t; i < ms; i += 256) {
        atomicAdd(&cntS2[(int)sBin[s0 + i]], 1);
    }
    __syncthreads();
    if (t < 64) {
        int v0 = cnt[t], v1 = cnt[64 + t];
        int i0 = v0;
        #pragma unroll
        for (int o = 1; o < 64; o <<= 1) { int n = __shfl_up(i0, o); if (t >= o) i0 += n; }
        excl[t] = i0 - v0;
        int tot0 = __shfl(i0, 63);
        int i1 = v1;
        #pragma unroll
        for (int o = 1; o < 64; o <<= 1) { int n = __shfl_up(i1, o); if (t >= o) i1 += n; }
        excl[64 + t] = tot0 + i1 - v1;
    }
    __syncthreads();
    if (t < 128) {
        int node = b * 128 + t;
        if (node < N_NODE) {
            rowptr[node] = e0 + excl[t];
            normR[node] = rsqrtf(fmaxf((float)cnt[t], 1.0f));
            normS[node] = rsqrtf(fmaxf((float)cntS2[t], 1.0f));
        }
    }
    if (b == NBUCK - 1 && t == 0) rowptr[N_NODE] = e1;
    for (int i = t; i < m; i += 256) {
        uint v = (i < STAGE_CAP) ? staged[i] : binned[e0 + i];
        int n7 = (int)(v & 127u);
        int lpos = atomicAdd(&cur[n7], 1);
        sortedSrc[e0 + excl[n7] + lpos] = (int)(v >> 7);
    }
}

// ---------------- weight prep: Wt[col][k] = bf16(W[k][col]) ----------------

__global__ __launch_bounds__(256)
void k_prepw(const float* __restrict__ W1, const float* __restrict__ W2,
             const float* __restrict__ W3,
             ushort_t* __restrict__ Wt1, ushort_t* __restrict__ Wt2,
             ushort_t* __restrict__ Wt3) {
    int i = blockIdx.x * 256 + threadIdx.x;
    if (i < 8192) {
        int col = i >> 7, k = i & 127;
        Wt1[i] = bf16r(W1[k * 64 + col]);
    } else if (i < 12288) {
        int j = i - 8192; int col = j >> 6, k = j & 63;
        Wt2[j] = bf16r(W2[k * 64 + col]);
    } else if (i < 14336) {
        int j = i - 12288; int col = j >> 6, k = j & 63;
        Wt3[j] = bf16r(W3[k * 32 + col]);
    }
}

// ---------------- MFMA dense transform ----------------

template<int K, int N, bool F32IN>
__global__ __launch_bounds__(256)
void k_mgemm(const void* __restrict__ Xv, const ushort_t* __restrict__ Wt,
             const float* __restrict__ bias, const float* __restrict__ normS,
             uint* __restrict__ Y2) {
    __shared__ uint WL[N * K / 2];
    const int tid = threadIdx.x, wave = tid >> 6, lane = tid & 63;
    const uint* Wg = (const uint*)Wt;
    for (int i = tid; i < N * K / 2; i += 256) {
        int col = i / (K / 2);
        WL[i ^ ((col & 7) << 2)] = Wg[i];
    }
    const int m0 = blockIdx.x * 64 + wave * 16;
    const int arow = m0 + (lane & 15);
    const int asrc = (arow < N_NODE) ? arow : 0;
    const int koff = (lane >> 4) * 8;
    bf16x8 afr[K / 32];
    if (F32IN) {
        const float* Xf = (const float*)Xv + (size_t)asrc * K + koff;
        #pragma unroll
        for (int s = 0; s < K / 32; ++s) {
            float4 u = *(const float4*)(Xf + 32 * s);
            float4 v = *(const float4*)(Xf + 32 * s + 4);
            union { uint u4[4]; bf16x8 v8; } c;
            c.u4[0] = bfpack(u.x, u.y); c.u4[1] = bfpack(u.z, u.w);
            c.u4[2] = bfpack(v.x, v.y); c.u4[3] = bfpack(v.z, v.w);
            afr[s] = c.v8;
        }
    } else {
        const uint* Xp = (const uint*)Xv + (size_t)asrc * (K / 2) + (koff >> 1);
        #pragma unroll
        for (int s = 0; s < K / 32; ++s) {
            uint2 q0 = *(const uint2*)(Xp + 16 * s);
            uint2 q1 = *(const uint2*)(Xp + 16 * s + 2);
            union { uint u4[4]; bf16x8 v8; } c;
            c.u4[0] = q0.x; c.u4[1] = q0.y; c.u4[2] = q1.x; c.u4[3] = q1.y;
            afr[s] = c.v8;
        }
    }
    __syncthreads();
    f32x4 acc[N / 16];
    #pragma unroll
    for (int t = 0; t < N / 16; ++t) acc[t] = (f32x4){0.f, 0.f, 0.f, 0.f};
    #pragma unroll
    for (int s = 0; s < K / 32; ++s) {
        #pragma unroll
        for (int t = 0; t < N / 16; ++t) {
            int col = t * 16 + (lane & 15);
            int word = (col * (K / 2) + s * 16 + (koff >> 1)) ^ ((col & 7) << 2);
            bf16x8 bfr = *(const bf16x8*)&WL[word];
            acc[t] = __builtin_amdgcn_mfma_f32_16x16x32_bf16(afr[s], bfr, acc[t], 0, 0, 0);
        }
    }
    const int r0 = m0 + (lane >> 4) * 4;
    float ns[4];
    #pragma unroll
    for (int i = 0; i < 4; ++i) ns[i] = (r0 + i < N_NODE) ? normS[r0 + i] : 0.f;
    #pragma unroll
    for (int t = 0; t < N / 16; ++t) {
        int col = t * 16 + (lane & 15);
        float bv = bias[col];
        #pragma unroll
        for (int i = 0; i < 4; ++i) {
            float v = (acc[t][i] + bv) * ns[i];
            float w = __shfl_down(v, 1);
            if ((lane & 1) == 0 && r0 + i < N_NODE)
                Y2[(size_t)(r0 + i) * (N / 2) + (col >> 1)] = bfpack(v, w);
        }
    }
}

// ---------------- aggregation variants ----------------

// A: feature-sliced pass — aggregates SLICE_U uints (=2*SLICE_U bf16) at uint-offset off0.
// Working set per pass = N_NODE*SLICE_U*4 bytes (3.2 MB for SLICE_U=8) -> L2-resident per XCD.
template<int F2, int SLICE_U, bool RELU>
__global__ __launch_bounds__(256)
void k_agg_slice(const uint* __restrict__ H2, const int* __restrict__ rowptr,
                 const int* __restrict__ srcs, const float* __restrict__ normR,
                 uint* __restrict__ Y2, int off0) {
    const int node = (blockIdx.x * 256 + threadIdx.x) >> 6;
    const int lane = threadIdx.x & 63;
    const int LPE = SLICE_U / 2;            // lanes per edge (uint2 each)
    const int PE  = 64 / LPE;               // edges in flight
    const int p = lane / LPE, q = lane % LPE;
    const int start = rowptr[node], end = rowptr[node + 1];
    float a0 = 0.f, a1 = 0.f, a2 = 0.f, a3 = 0.f;
    for (int e = start + p; e < end; e += PE) {
        int s = srcs[e];
        uint2 v = *(const uint2*)&H2[(size_t)s * F2 + off0 + q * 2];
        a0 += bflo(v.x); a1 += bfhi(v.x);
        a2 += bflo(v.y); a3 += bfhi(v.y);
    }
    #pragma unroll
    for (int m = LPE; m < 64; m <<= 1) {
        a0 += __shfl_xor(a0, m); a1 += __shfl_xor(a1, m);
        a2 += __shfl_xor(a2, m); a3 += __shfl_xor(a3, m);
    }
    if (lane < LPE) {
        float nr = normR[node];
        a0 *= nr; a1 *= nr; a2 *= nr; a3 *= nr;
        if (RELU) { a0 = fmaxf(a0, 0.f); a1 = fmaxf(a1, 0.f); a2 = fmaxf(a2, 0.f); a3 = fmaxf(a3, 0.f); }
        *(uint2*)&Y2[(size_t)node * F2 + off0 + q * 2] = make_uint2(bfpack(a0, a1), bfpack(a2, a3));
    }
}

// B: single-pass deep-ILP for F=64 — uint2 loads, 16 lanes/edge, 4 edges x unroll-4 = 16 edges in flight.
template<bool RELU>
__global__ __launch_bounds__(256)
void k_agg64v(const uint* __restrict__ H2, const int* __restrict__ rowptr,
              const int* __restrict__ srcs, const float* __restrict__ normR,
              uint* __restrict__ Y2) {
    const int node = (blockIdx.x * 256 + threadIdx.x) >> 6;
    const int lane = threadIdx.x & 63;
    const int p = lane >> 4;                // edge slot 0..3
    const int q = lane & 15;                // uint2 offset within 32-uint row
    const int start = rowptr[node], end = rowptr[node + 1];
    float a0 = 0.f, a1 = 0.f, a2 = 0.f, a3 = 0.f;
    int e = start + p;
    for (; e + 12 < end; e += 16) {
        int s0 = srcs[e], s1 = srcs[e + 4], s2 = srcs[e + 8], s3 = srcs[e + 12];
        uint2 v0 = *(const uint2*)&H2[(size_t)s0 * 32 + q * 2];
        uint2 v1 = *(const uint2*)&H2[(size_t)s1 * 32 + q * 2];
        uint2 v2 = *(const uint2*)&H2[(size_t)s2 * 32 + q * 2];
        uint2 v3 = *(const uint2*)&H2[(size_t)s3 * 32 + q * 2];
        a0 += bflo(v0.x); a1 += bfhi(v0.x); a2 += bflo(v0.y); a3 += bfhi(v0.y);
        a0 += bflo(v1.x); a1 += bfhi(v1.x); a2 += bflo(v1.y); a3 += bfhi(v1.y);
        a0 += bflo(v2.x); a1 += bfhi(v2.x); a2 += bflo(v2.y); a3 += bfhi(v2.y);
        a0 += bflo(v3.x); a1 += bfhi(v3.x); a2 += bflo(v3.y); a3 += bfhi(v3.y);
    }
    for (; e < end; e += 4) {
        int s = srcs[e];
        uint2 v = *(const uint2*)&H2[(size_t)s * 32 + q * 2];
        a0 += bflo(v.x); a1 += bfhi(v.x); a2 += bflo(v.y); a3 += bfhi(v.y);
    }
    a0 += __shfl_xor(a0, 16); a1 += __shfl_xor(a1, 16);
    a2 += __shfl_xor(a2, 16); a3 += __shfl_xor(a3, 16);
    a0 += __shfl_xor(a0, 32); a1 += __shfl_xor(a1, 32);
    a2 += __shfl_xor(a2, 32); a3 += __shfl_xor(a3, 32);
    if (lane < 16) {
        float nr = normR[node];
        a0 *= nr; a1 *= nr; a2 *= nr; a3 *= nr;
        if (RELU) { a0 = fmaxf(a0, 0.f); a1 = fmaxf(a1, 0.f); a2 = fmaxf(a2, 0.f); a3 = fmaxf(a3, 0.f); }
        *(uint2*)&Y2[(size_t)node * 32 + q * 2] = make_uint2(bfpack(a0, a1), bfpack(a2, a3));
    }
}

// C: control — original scalar-load agg (used for layer 3, F=32)
template<int F, bool RELU>
__global__ __launch_bounds__(256)
void k_agg(const uint* __restrict__ H2, const int* __restrict__ rowptr,
           const int* __restrict__ srcs, const float* __restrict__ normR,
           uint* __restrict__ Y2) {
    const int node = (blockIdx.x * 256 + threadIdx.x) >> 6;
    const int lane = threadIdx.x & 63;
    const int F2 = F / 2;
    const int PE = 64 / F2;
    const int sub = lane / F2;
    const int fj = lane % F2;
    const int start = rowptr[node], end = rowptr[node + 1];
    float a0 = 0.0f, a1 = 0.0f;
    int e = start + sub;
    for (; e + 3 * PE < end; e += 4 * PE) {
        int s0 = srcs[e], s1 = srcs[e + PE], s2 = srcs[e + 2 * PE], s3 = srcs[e + 3 * PE];
        uint p0 = H2[s0 * F2 + fj];
        uint p1 = H2[s1 * F2 + fj];
        uint p2 = H2[s2 * F2 + fj];
        uint p3 = H2[s3 * F2 + fj];
        a0 += bflo(p0); a1 += bfhi(p0);
        a0 += bflo(p1); a1 += bfhi(p1);
        a0 += bflo(p2); a1 += bfhi(p2);
        a0 += bflo(p3); a1 += bfhi(p3);
    }
    for (; e < end; e += PE) {
        uint p = H2[srcs[e] * F2 + fj];
        a0 += bflo(p); a1 += bfhi(p);
    }
    if (PE == 4) { a0 += __shfl_xor(a0, 16); a1 += __shfl_xor(a1, 16); }
    a0 += __shfl_xor(a0, 32); a1 += __shfl_xor(a1, 32);
    if (lane < F2) {
        float nr = normR[node];
        float r0 = a0 * nr, r1 = a1 * nr;
        if (RELU) { r0 = fmaxf(r0, 0.0f); r1 = fmaxf(r1, 0.0f); }
        Y2[node * F2 + fj] = bfpack(r0, r1);
    }
}

// ---------------- graph pooling ----------------

__global__ __launch_bounds__(256)
void k_pool(const uint* __restrict__ H2, const int* __restrict__ batch,
            float* __restrict__ out) {
    const int wid = (blockIdx.x * 256 + threadIdx.x) >> 6;
    const int lane = threadIdx.x & 63;
    const int NPW = (N_NODE + 1023) / 1024;
    int n0 = wid * NPW, n1 = min(n0 + NPW, N_NODE);
    const int p = lane >> 4, fj = lane & 15;
    float a0 = 0.0f, a1 = 0.0f;
    int gCur = -1;
    for (int n = n0 + p; n < n1; n += 4) {
        int g = batch[n];
        uint v = H2[n * 16 + fj];
        if (g != gCur) {
            if (gCur >= 0) {
                atomicAdd(&out[gCur * OUT_DIM + 2 * fj], a0);
                atomicAdd(&out[gCur * OUT_DIM + 2 * fj + 1], a1);
            }
            gCur = g; a0 = bflo(v); a1 = bfhi(v);
        } else {
            a0 += bflo(v); a1 += bfhi(v);
        }
    }
    if (gCur >= 0) {
        atomicAdd(&out[gCur * OUT_DIM + 2 * fj], a0);
        atomicAdd(&out[gCur * OUT_DIM + 2 * fj + 1], a1);
    }
}

// ---------------- launch ----------------

extern "C" void kernel_launch(void* const* d_in, const int* in_sizes, int n_in,
                              void* d_out, int out_size, void* d_ws, size_t ws_size,
                              hipStream_t stream) {
    const float* x   = (const float*)d_in[0];
    const float* W1  = (const float*)d_in[1];
    const float* b1  = (const float*)d_in[2];
    const float* W2  = (const float*)d_in[3];
    const float* b2  = (const float*)d_in[4];
    const float* W3  = (const float*)d_in[5];
    const float* b3  = (const float*)d_in[6];
    const int* snd   = (const int*)d_in[7];
    const int* rcv   = (const int*)d_in[8];
    const int* batch = (const int*)d_in[9];
    float* out = (float*)d_out;

    char* ws = (char*)d_ws;
    size_t off = 0;
    auto carve = [&](size_t bytes) { char* p = ws + off; off += (bytes + 15) & ~size_t(15); return p; };
    int*   cntRA       = (int*)  carve((size_t)BBLK * NBUCK * 4);
    int*   cntSA       = (int*)  carve((size_t)BBLK * NBUCK * 4);
    int*   rTotal      = (int*)  carve(NBUCK * 4);
    int*   sTotal      = (int*)  carve(NBUCK * 4);
    int*   rBase       = (int*)  carve((NBUCK + 1) * 4);
    int*   sBase       = (int*)  carve((NBUCK + 1) * 4);
    int*   rowptr      = (int*)  carve((N_NODE + 1) * 4);
    uint*  binned      = (uint*) carve((size_t)N_EDGE * 4);
    uchar* sBin        = (uchar*)carve((size_t)N_EDGE);
    int*   sortedSrc   = (int*)  carve((size_t)N_EDGE * 4);
    float* normS       = (float*)carve(N_NODE * 4);
    float* normR       = (float*)carve(N_NODE * 4);
    ushort_t* Wt1      = (ushort_t*)carve(8192 * 2);
    ushort_t* Wt2      = (ushort_t*)carve(4096 * 2);
    ushort_t* Wt3      = (ushort_t*)carve(2048 * 2);
    uint*  bufA        = (uint*) carve((size_t)N_NODE * 32 * 4);
    uint*  bufB        = (uint*) carve((size_t)N_NODE * 32 * 4);

    hipMemsetAsync(d_out, 0, NUM_GRAPHS * OUT_DIM * 4, stream);

    k_prepw<<<56, 256, 0, stream>>>(W1, W2, W3, Wt1, Wt2, Wt3);
    k_count<<<BBLK, 256, 0, stream>>>((const int2*)snd, (const int2*)rcv, cntRA, cntSA);
    k_scanb<<<2 * NBUCK, 256, 0, stream>>>(cntRA, cntSA, rTotal, sTotal);
    k_scanB<<<2, 256, 0, stream>>>(rTotal, sTotal, rBase, sBase);
    k_place<<<BBLK, 256, 0, stream>>>((const int2*)snd, (const int2*)rcv, cntRA, cntSA,
                                      rBase, sBase, binned, sBin);
    k_local<<<NBUCK, 256, 0, stream>>>(binned, sBin, rBase, sBase,
                                       rowptr, normS, normR, sortedSrc);

    const int AGG_B = (N_NODE * 64 + 255) / 256;   // one wave per node
    const int GB = (N_NODE + 63) / 64;             // MFMA blocks

    // layer 1: 128 -> 64, relu -- VARIANT A: feature-sliced agg (4 passes, L2-resident slices)
    k_mgemm<IN_DIM, HID1, true><<<GB, 256, 0, stream>>>(x, Wt1, b1, normS, bufA);
    k_agg_slice<32, 8, true><<<AGG_B, 256, 0, stream>>>(bufA, rowptr, sortedSrc, normR, bufB, 0);
    k_agg_slice<32, 8, true><<<AGG_B, 256, 0, stream>>>(bufA, rowptr, sortedSrc, normR, bufB, 8);
    k_agg_slice<32, 8, true><<<AGG_B, 256, 0, stream>>>(bufA, rowptr, sortedSrc, normR, bufB, 16);
    k_agg_slice<32, 8, true><<<AGG_B, 256, 0, stream>>>(bufA, rowptr, sortedSrc, normR, bufB, 24);

    // layer 2: 64 -> 64, relu -- VARIANT B: single-pass deep-ILP vectorized agg
    k_mgemm<HID1, HID2, false><<<GB, 256, 0, stream>>>(bufB, Wt2, b2, normS, bufA);
    k_agg64v<true><<<AGG_B, 256, 0, stream>>>(bufA, rowptr, sortedSrc, normR, bufB);

    // layer 3: 64 -> 32, no relu -- CONTROL: original agg
    k_mgemm<HID2, OUT_DIM, false><<<GB, 256, 0, stream>>>(bufB, Wt3, b3, normS, bufA);
    k_agg<OUT_DIM, false><<<AGG_B, 256, 0, stream>>>(bufA, rowptr, sortedSrc, normR, bufB);

    // pooling
    k_pool<<<256, 256, 0, stream>>>(bufB, batch, out);
}

// Round 11
// 352.020 us; speedup vs baseline: 1.3371x; 1.3371x over previous
//
#include <hip/hip_runtime.h>
#include <hip/hip_bf16.h>

#define N_NODE   100000
#define N_EDGE   1600000
#define IN_DIM   128
#define HID1     64
#define HID2     64
#define OUT_DIM  32
#define NUM_GRAPHS 256

#define NBUCK    782            // ceil(100000/128) node buckets of 128
#define BBLK     500            // binning blocks
#define EPB      3200           // edges per binning block (500*3200 = 1.6M exact)
#define STAGE_CAP 8192          // LDS staging capacity in k_local2 (avg bucket ~2046)

typedef unsigned int uint;
typedef unsigned char uchar;
typedef unsigned short ushort_t;
typedef short bf16x8 __attribute__((ext_vector_type(8)));
typedef float f32x4 __attribute__((ext_vector_type(4)));

__device__ __forceinline__ float bflo(uint p) { return __uint_as_float(p << 16); }
__device__ __forceinline__ float bfhi(uint p) { return __uint_as_float(p & 0xFFFF0000u); }
__device__ __forceinline__ uint bfpack(float a, float b) {
    uint ua = __float_as_uint(a), ub = __float_as_uint(b);
    ua = (ua + 0x7FFFu + ((ua >> 16) & 1u)) >> 16;
    ub = (ub + 0x7FFFu + ((ub >> 16) & 1u)) & 0xFFFF0000u;
    return ua | ub;
}
__device__ __forceinline__ ushort_t bf16r(float f) {
    uint ua = __float_as_uint(f);
    return (ushort_t)((ua + 0x7FFFu + ((ua >> 16) & 1u)) >> 16);
}

// block-wide exclusive scan of hist[0..NBUCK) in LDS; hist[NBUCK] = total
__device__ __forceinline__ void scan_lds(int* hist, int t, int lane, int wave, int* sW) {
    int carry = 0;
    for (int k = 0; k < 4; ++k) {
        int idx = k * 256 + t;
        int v = (idx < NBUCK) ? hist[idx] : 0;
        int inc = v;
        #pragma unroll
        for (int o = 1; o < 64; o <<= 1) { int n = __shfl_up(inc, o); if (lane >= o) inc += n; }
        if (lane == 63) sW[wave] = inc;
        __syncthreads();
        int wOff = 0;
        for (int w = 0; w < wave; ++w) wOff += sW[w];
        int tot = sW[0] + sW[1] + sW[2] + sW[3];
        int excl = carry + wOff + inc - v;
        __syncthreads();
        if (idx < NBUCK) hist[idx] = excl;
        carry += tot;
        __syncthreads();
    }
    if (t == 0) hist[NBUCK] = carry;
    __syncthreads();
}

// ---------------- preprocessing: block-major binned CSR build ----------------
// k_place2: one pass over edges; per-block LDS histograms (recv+send buckets),
// in-LDS scan, in-LDS placement, fully-coalesced stream-out. No global atomics,
// no scattered global writes.

__global__ __launch_bounds__(256)
void k_place2(const int2* __restrict__ snd2, const int2* __restrict__ rcv2,
              int* __restrict__ localOffR, int* __restrict__ localOffS,   // [BBLK][NBUCK+1]
              uint* __restrict__ binned2, uint* __restrict__ sBin2u) {
    __shared__ int histR[NBUCK + 1];
    __shared__ int histS[NBUCK + 1];
    __shared__ int curR[NBUCK];
    __shared__ int curS[NBUCK];
    __shared__ uint bufR[EPB];
    __shared__ uint bufSu[EPB / 4];
    __shared__ int sW[4];
    const int t = threadIdx.x, blk = blockIdx.x, lane = t & 63, wave = t >> 6;
    for (int i = t; i < NBUCK + 1; i += 256) { histR[i] = 0; histS[i] = 0; }
    for (int i = t; i < NBUCK; i += 256) { curR[i] = 0; curS[i] = 0; }
    __syncthreads();
    const int base2 = blk * (EPB / 2);
    int2 rs[7], ss[7];
    #pragma unroll
    for (int i = 0; i < 7; ++i) {
        int l2 = i * 256 + t;
        if (l2 < EPB / 2) {
            rs[i] = rcv2[base2 + l2];
            ss[i] = snd2[base2 + l2];
            atomicAdd(&histR[rs[i].x >> 7], 1);
            atomicAdd(&histR[rs[i].y >> 7], 1);
            atomicAdd(&histS[ss[i].x >> 7], 1);
            atomicAdd(&histS[ss[i].y >> 7], 1);
        }
    }
    __syncthreads();
    scan_lds(histR, t, lane, wave, sW);
    scan_lds(histS, t, lane, wave, sW);
    // persist per-block bucket offsets (coalesced)
    for (int i = t; i < NBUCK + 1; i += 256) {
        localOffR[(size_t)blk * (NBUCK + 1) + i] = histR[i];
        localOffS[(size_t)blk * (NBUCK + 1) + i] = histS[i];
    }
    // place into LDS
    uchar* bufS = (uchar*)bufSu;
    #pragma unroll
    for (int i = 0; i < 7; ++i) {
        int l2 = i * 256 + t;
        if (l2 < EPB / 2) {
            int2 r = rs[i], s = ss[i];
            int b0 = r.x >> 7, b1 = r.y >> 7;
            int p0 = atomicAdd(&curR[b0], 1);
            bufR[histR[b0] + p0] = ((uint)s.x << 7) | (uint)(r.x & 127);
            int p1 = atomicAdd(&curR[b1], 1);
            bufR[histR[b1] + p1] = ((uint)s.y << 7) | (uint)(r.y & 127);
            int c0 = s.x >> 7, c1 = s.y >> 7;
            int q0 = atomicAdd(&curS[c0], 1);
            bufS[histS[c0] + q0] = (uchar)(s.x & 127);
            int q1 = atomicAdd(&curS[c1], 1);
            bufS[histS[c1] + q1] = (uchar)(s.y & 127);
        }
    }
    __syncthreads();
    // stream out coalesced
    for (int i = t; i < EPB; i += 256) binned2[(size_t)blk * EPB + i] = bufR[i];
    for (int i = t; i < EPB / 4; i += 256) sBin2u[(size_t)blk * (EPB / 4) + i] = bufSu[i];
}

// receiver-bucket totals from localOffR deltas
__global__ __launch_bounds__(256)
void k_totals(const int* __restrict__ localOffR, int* __restrict__ rTotal) {
    const int b = blockIdx.x, t = threadIdx.x, lane = t & 63, wave = t >> 6;
    int sum = 0;
    for (int blk = t; blk < BBLK; blk += 256) {
        size_t base = (size_t)blk * (NBUCK + 1) + b;
        sum += localOffR[base + 1] - localOffR[base];
    }
    #pragma unroll
    for (int o = 1; o < 64; o <<= 1) sum += __shfl_xor(sum, o);
    __shared__ int sw[4];
    if (lane == 0) sw[wave] = sum;
    __syncthreads();
    if (t == 0) rTotal[b] = sw[0] + sw[1] + sw[2] + sw[3];
}

// scan bucket totals -> rBase[0..NBUCK]
__global__ __launch_bounds__(256)
void k_scanB(const int* __restrict__ rTotal, int* __restrict__ rBase) {
    const int t = threadIdx.x, lane = t & 63, wave = t >> 6;
    __shared__ int sW[4];
    int carry = 0;
    for (int k = 0; k < 4; ++k) {
        int idx = k * 256 + t;
        int v = (idx < NBUCK) ? rTotal[idx] : 0;
        int inc = v;
        #pragma unroll
        for (int o = 1; o < 64; o <<= 1) { int n = __shfl_up(inc, o); if (lane >= o) inc += n; }
        if (lane == 63) sW[wave] = inc;
        __syncthreads();
        int wOff = 0;
        for (int w = 0; w < wave; ++w) wOff += sW[w];
        int tot = sW[0] + sW[1] + sW[2] + sW[3];
        int excl = carry + wOff + inc - v;
        if (idx < NBUCK) rBase[idx] = excl;
        carry += tot;
        __syncthreads();
    }
    if (t == 0) rBase[NBUCK] = carry;
}

// per-bucket: gather block-major segments, histogram, scan -> rowptr/normR/normS, place sortedSrc
__global__ __launch_bounds__(256)
void k_local2(const uint* __restrict__ binned2, const uchar* __restrict__ sBin2,
              const int* __restrict__ localOffR, const int* __restrict__ localOffS,
              const int* __restrict__ rBase,
              int* __restrict__ rowptr, float* __restrict__ normS, float* __restrict__ normR,
              int* __restrict__ sortedSrc) {
    __shared__ uint staged[STAGE_CAP];
    __shared__ int cnt[128], excl[128], cur[128], cntS2[128];
    __shared__ int cursor;
    const int b = blockIdx.x, t = threadIdx.x;
    const int e0 = rBase[b], e1 = rBase[b + 1], m = e1 - e0;
    if (t < 128) { cnt[t] = 0; cur[t] = 0; cntS2[t] = 0; }
    if (t == 0) cursor = 0;
    __syncthreads();
    for (int blk = t; blk < BBLK; blk += 256) {
        size_t base = (size_t)blk * (NBUCK + 1) + b;
        int o0 = localOffR[base], o1 = localOffR[base + 1];
        int len = o1 - o0;
        if (len > 0) {
            int pos = atomicAdd(&cursor, len);
            const uint* src = binned2 + (size_t)blk * EPB + o0;
            for (int i = 0; i < len; ++i) {
                uint v = src[i];
                staged[pos + i] = v;
                atomicAdd(&cnt[v & 127u], 1);
            }
        }
        int so0 = localOffS[base], so1 = localOffS[base + 1];
        const uchar* ssrc = sBin2 + (size_t)blk * EPB;
        for (int i = so0; i < so1; ++i) atomicAdd(&cntS2[(int)ssrc[i]], 1);
    }
    __syncthreads();
    if (t < 64) {
        int v0 = cnt[t], v1 = cnt[64 + t];
        int i0 = v0;
        #pragma unroll
        for (int o = 1; o < 64; o <<= 1) { int n = __shfl_up(i0, o); if (t >= o) i0 += n; }
        excl[t] = i0 - v0;
        int tot0 = __shfl(i0, 63);
        int i1 = v1;
        #pragma unroll
        for (int o = 1; o < 64; o <<= 1) { int n = __shfl_up(i1, o); if (t >= o) i1 += n; }
        excl[64 + t] = tot0 + i1 - v1;
    }
    __syncthreads();
    if (t < 128) {
        int node = b * 128 + t;
        if (node < N_NODE) {
            rowptr[node] = e0 + excl[t];
            normR[node] = rsqrtf(fmaxf((float)cnt[t], 1.0f));
            normS[node] = rsqrtf(fmaxf((float)cntS2[t], 1.0f));
        }
    }
    if (b == NBUCK - 1 && t == 0) rowptr[N_NODE] = e1;
    for (int i = t; i < m; i += 256) {
        uint v = staged[i];
        int n7 = (int)(v & 127u);
        int lpos = atomicAdd(&cur[n7], 1);
        sortedSrc[e0 + excl[n7] + lpos] = (int)(v >> 7);
    }
}

// ---------------- weight prep: Wt[col][k] = bf16(W[k][col]) ----------------

__global__ __launch_bounds__(256)
void k_prepw(const float* __restrict__ W1, const float* __restrict__ W2,
             const float* __restrict__ W3,
             ushort_t* __restrict__ Wt1, ushort_t* __restrict__ Wt2,
             ushort_t* __restrict__ Wt3) {
    int i = blockIdx.x * 256 + threadIdx.x;
    if (i < 8192) {
        int col = i >> 7, k = i & 127;
        Wt1[i] = bf16r(W1[k * 64 + col]);
    } else if (i < 12288) {
        int j = i - 8192; int col = j >> 6, k = j & 63;
        Wt2[j] = bf16r(W2[k * 64 + col]);
    } else if (i < 14336) {
        int j = i - 12288; int col = j >> 6, k = j & 63;
        Wt3[j] = bf16r(W3[k * 32 + col]);
    }
}

// ---------------- MFMA dense transform ----------------

template<int K, int N, bool F32IN>
__global__ __launch_bounds__(256)
void k_mgemm(const void* __restrict__ Xv, const ushort_t* __restrict__ Wt,
             const float* __restrict__ bias, const float* __restrict__ normS,
             uint* __restrict__ Y2) {
    __shared__ uint WL[N * K / 2];
    const int tid = threadIdx.x, wave = tid >> 6, lane = tid & 63;
    const uint* Wg = (const uint*)Wt;
    for (int i = tid; i < N * K / 2; i += 256) {
        int col = i / (K / 2);
        WL[i ^ ((col & 7) << 2)] = Wg[i];
    }
    const int m0 = blockIdx.x * 64 + wave * 16;
    const int arow = m0 + (lane & 15);
    const int asrc = (arow < N_NODE) ? arow : 0;
    const int koff = (lane >> 4) * 8;
    bf16x8 afr[K / 32];
    if (F32IN) {
        const float* Xf = (const float*)Xv + (size_t)asrc * K + koff;
        #pragma unroll
        for (int s = 0; s < K / 32; ++s) {
            float4 u = *(const float4*)(Xf + 32 * s);
            float4 v = *(const float4*)(Xf + 32 * s + 4);
            union { uint u4[4]; bf16x8 v8; } c;
            c.u4[0] = bfpack(u.x, u.y); c.u4[1] = bfpack(u.z, u.w);
            c.u4[2] = bfpack(v.x, v.y); c.u4[3] = bfpack(v.z, v.w);
            afr[s] = c.v8;
        }
    } else {
        const uint* Xp = (const uint*)Xv + (size_t)asrc * (K / 2) + (koff >> 1);
        #pragma unroll
        for (int s = 0; s < K / 32; ++s) {
            uint2 q0 = *(const uint2*)(Xp + 16 * s);
            uint2 q1 = *(const uint2*)(Xp + 16 * s + 2);
            union { uint u4[4]; bf16x8 v8; } c;
            c.u4[0] = q0.x; c.u4[1] = q0.y; c.u4[2] = q1.x; c.u4[3] = q1.y;
            afr[s] = c.v8;
        }
    }
    __syncthreads();
    f32x4 acc[N / 16];
    #pragma unroll
    for (int t = 0; t < N / 16; ++t) acc[t] = (f32x4){0.f, 0.f, 0.f, 0.f};
    #pragma unroll
    for (int s = 0; s < K / 32; ++s) {
        #pragma unroll
        for (int t = 0; t < N / 16; ++t) {
            int col = t * 16 + (lane & 15);
            int word = (col * (K / 2) + s * 16 + (koff >> 1)) ^ ((col & 7) << 2);
            bf16x8 bfr = *(const bf16x8*)&WL[word];
            acc[t] = __builtin_amdgcn_mfma_f32_16x16x32_bf16(afr[s], bfr, acc[t], 0, 0, 0);
        }
    }
    const int r0 = m0 + (lane >> 4) * 4;
    float ns[4];
    #pragma unroll
    for (int i = 0; i < 4; ++i) ns[i] = (r0 + i < N_NODE) ? normS[r0 + i] : 0.f;
    #pragma unroll
    for (int t = 0; t < N / 16; ++t) {
        int col = t * 16 + (lane & 15);
        float bv = bias[col];
        #pragma unroll
        for (int i = 0; i < 4; ++i) {
            float v = (acc[t][i] + bv) * ns[i];
            float w = __shfl_down(v, 1);
            if ((lane & 1) == 0 && r0 + i < N_NODE)
                Y2[(size_t)(r0 + i) * (N / 2) + (col >> 1)] = bfpack(v, w);
        }
    }
}

// ---------------- aggregation ----------------

// F=64: uint2 loads, 16 lanes/edge, 4 edges x unroll-4 = 16 edges in flight
template<bool RELU>
__global__ __launch_bounds__(256)
void k_agg64v(const uint* __restrict__ H2, const int* __restrict__ rowptr,
              const int* __restrict__ srcs, const float* __restrict__ normR,
              uint* __restrict__ Y2) {
    const int node = (blockIdx.x * 256 + threadIdx.x) >> 6;
    const int lane = threadIdx.x & 63;
    const int p = lane >> 4;
    const int q = lane & 15;
    const int start = rowptr[node], end = rowptr[node + 1];
    float a0 = 0.f, a1 = 0.f, a2 = 0.f, a3 = 0.f;
    int e = start + p;
    for (; e + 12 < end; e += 16) {
        int s0 = srcs[e], s1 = srcs[e + 4], s2 = srcs[e + 8], s3 = srcs[e + 12];
        uint2 v0 = *(const uint2*)&H2[(size_t)s0 * 32 + q * 2];
        uint2 v1 = *(const uint2*)&H2[(size_t)s1 * 32 + q * 2];
        uint2 v2 = *(const uint2*)&H2[(size_t)s2 * 32 + q * 2];
        uint2 v3 = *(const uint2*)&H2[(size_t)s3 * 32 + q * 2];
        a0 += bflo(v0.x); a1 += bfhi(v0.x); a2 += bflo(v0.y); a3 += bfhi(v0.y);
        a0 += bflo(v1.x); a1 += bfhi(v1.x); a2 += bflo(v1.y); a3 += bfhi(v1.y);
        a0 += bflo(v2.x); a1 += bfhi(v2.x); a2 += bflo(v2.y); a3 += bfhi(v2.y);
        a0 += bflo(v3.x); a1 += bfhi(v3.x); a2 += bflo(v3.y); a3 += bfhi(v3.y);
    }
    for (; e < end; e += 4) {
        int s = srcs[e];
        uint2 v = *(const uint2*)&H2[(size_t)s * 32 + q * 2];
        a0 += bflo(v.x); a1 += bfhi(v.x); a2 += bflo(v.y); a3 += bfhi(v.y);
    }
    a0 += __shfl_xor(a0, 16); a1 += __shfl_xor(a1, 16);
    a2 += __shfl_xor(a2, 16); a3 += __shfl_xor(a3, 16);
    a0 += __shfl_xor(a0, 32); a1 += __shfl_xor(a1, 32);
    a2 += __shfl_xor(a2, 32); a3 += __shfl_xor(a3, 32);
    if (lane < 16) {
        float nr = normR[node];
        a0 *= nr; a1 *= nr; a2 *= nr; a3 *= nr;
        if (RELU) { a0 = fmaxf(a0, 0.f); a1 = fmaxf(a1, 0.f); a2 = fmaxf(a2, 0.f); a3 = fmaxf(a3, 0.f); }
        *(uint2*)&Y2[(size_t)node * 32 + q * 2] = make_uint2(bfpack(a0, a1), bfpack(a2, a3));
    }
}

// F=32: uint2 loads, 8 lanes/edge, 8 edges x unroll-2 = 16 edges in flight
template<bool RELU>
__global__ __launch_bounds__(256)
void k_agg32v(const uint* __restrict__ H2, const int* __restrict__ rowptr,
              const int* __restrict__ srcs, const float* __restrict__ normR,
              uint* __restrict__ Y2) {
    const int node = (blockIdx.x * 256 + threadIdx.x) >> 6;
    const int lane = threadIdx.x & 63;
    const int p = lane >> 3;
    const int q = lane & 7;
    const int start = rowptr[node], end = rowptr[node + 1];
    float a0 = 0.f, a1 = 0.f, a2 = 0.f, a3 = 0.f;
    int e = start + p;
    for (; e + 8 < end; e += 16) {
        int s0 = srcs[e], s1 = srcs[e + 8];
        uint2 v0 = *(const uint2*)&H2[(size_t)s0 * 16 + q * 2];
        uint2 v1 = *(const uint2*)&H2[(size_t)s1 * 16 + q * 2];
        a0 += bflo(v0.x); a1 += bfhi(v0.x); a2 += bflo(v0.y); a3 += bfhi(v0.y);
        a0 += bflo(v1.x); a1 += bfhi(v1.x); a2 += bflo(v1.y); a3 += bfhi(v1.y);
    }
    for (; e < end; e += 8) {
        int s = srcs[e];
        uint2 v = *(const uint2*)&H2[(size_t)s * 16 + q * 2];
        a0 += bflo(v.x); a1 += bfhi(v.x); a2 += bflo(v.y); a3 += bfhi(v.y);
    }
    #pragma unroll
    for (int m = 8; m < 64; m <<= 1) {
        a0 += __shfl_xor(a0, m); a1 += __shfl_xor(a1, m);
        a2 += __shfl_xor(a2, m); a3 += __shfl_xor(a3, m);
    }
    if (lane < 8) {
        float nr = normR[node];
        a0 *= nr; a1 *= nr; a2 *= nr; a3 *= nr;
        if (RELU) { a0 = fmaxf(a0, 0.f); a1 = fmaxf(a1, 0.f); a2 = fmaxf(a2, 0.f); a3 = fmaxf(a3, 0.f); }
        *(uint2*)&Y2[(size_t)node * 16 + q * 2] = make_uint2(bfpack(a0, a1), bfpack(a2, a3));
    }
}

// ---------------- graph pooling (batch sorted -> run-based accumulation) ----------------

__global__ __launch_bounds__(256)
void k_pool(const uint* __restrict__ H2, const int* __restrict__ batch,
            float* __restrict__ out) {
    const int wid = (blockIdx.x * 256 + threadIdx.x) >> 6;
    const int lane = threadIdx.x & 63;
    const int NPW = (N_NODE + 1023) / 1024;
    int n0 = wid * NPW, n1 = min(n0 + NPW, N_NODE);
    const int p = lane >> 4, fj = lane & 15;
    float a0 = 0.0f, a1 = 0.0f;
    int gCur = -1;
    for (int n = n0 + p; n < n1; n += 4) {
        int g = batch[n];
        uint v = H2[n * 16 + fj];
        if (g != gCur) {
            if (gCur >= 0) {
                atomicAdd(&out[gCur * OUT_DIM + 2 * fj], a0);
                atomicAdd(&out[gCur * OUT_DIM + 2 * fj + 1], a1);
            }
            gCur = g; a0 = bflo(v); a1 = bfhi(v);
        } else {
            a0 += bflo(v); a1 += bfhi(v);
        }
    }
    if (gCur >= 0) {
        atomicAdd(&out[gCur * OUT_DIM + 2 * fj], a0);
        atomicAdd(&out[gCur * OUT_DIM + 2 * fj + 1], a1);
    }
}

// ---------------- launch ----------------

extern "C" void kernel_launch(void* const* d_in, const int* in_sizes, int n_in,
                              void* d_out, int out_size, void* d_ws, size_t ws_size,
                              hipStream_t stream) {
    const float* x   = (const float*)d_in[0];
    const float* W1  = (const float*)d_in[1];
    const float* b1  = (const float*)d_in[2];
    const float* W2  = (const float*)d_in[3];
    const float* b2  = (const float*)d_in[4];
    const float* W3  = (const float*)d_in[5];
    const float* b3  = (const float*)d_in[6];
    const int* snd   = (const int*)d_in[7];
    const int* rcv   = (const int*)d_in[8];
    const int* batch = (const int*)d_in[9];
    float* out = (float*)d_out;

    char* ws = (char*)d_ws;
    size_t off = 0;
    auto carve = [&](size_t bytes) { char* p = ws + off; off += (bytes + 15) & ~size_t(15); return p; };
    int*   localOffR   = (int*)  carve((size_t)BBLK * (NBUCK + 1) * 4);   // 1.57 MB
    int*   localOffS   = (int*)  carve((size_t)BBLK * (NBUCK + 1) * 4);   // 1.57 MB
    int*   rTotal      = (int*)  carve(NBUCK * 4);
    int*   rBase       = (int*)  carve((NBUCK + 1) * 4);
    int*   rowptr      = (int*)  carve((N_NODE + 1) * 4);
    uint*  binned2     = (uint*) carve((size_t)N_EDGE * 4);               // 6.4 MB
    uint*  sBin2u      = (uint*) carve((size_t)N_EDGE);                   // 1.6 MB
    int*   sortedSrc   = (int*)  carve((size_t)N_EDGE * 4);               // 6.4 MB
    float* normS       = (float*)carve(N_NODE * 4);
    float* normR       = (float*)carve(N_NODE * 4);
    ushort_t* Wt1      = (ushort_t*)carve(8192 * 2);
    ushort_t* Wt2      = (ushort_t*)carve(4096 * 2);
    ushort_t* Wt3      = (ushort_t*)carve(2048 * 2);
    uint*  bufA        = (uint*) carve((size_t)N_NODE * 32 * 4);
    uint*  bufB        = (uint*) carve((size_t)N_NODE * 32 * 4);

    hipMemsetAsync(d_out, 0, NUM_GRAPHS * OUT_DIM * 4, stream);

    k_prepw<<<56, 256, 0, stream>>>(W1, W2, W3, Wt1, Wt2, Wt3);
    k_place2<<<BBLK, 256, 0, stream>>>((const int2*)snd, (const int2*)rcv,
                                       localOffR, localOffS, binned2, sBin2u);
    k_totals<<<NBUCK, 256, 0, stream>>>(localOffR, rTotal);
    k_scanB<<<1, 256, 0, stream>>>(rTotal, rBase);
    k_local2<<<NBUCK, 256, 0, stream>>>(binned2, (const uchar*)sBin2u,
                                        localOffR, localOffS, rBase,
                                        rowptr, normS, normR, sortedSrc);

    const int AGG_B = (N_NODE * 64 + 255) / 256;   // one wave per node
    const int GB = (N_NODE + 63) / 64;             // MFMA blocks

    // layer 1: 128 -> 64, relu
    k_mgemm<IN_DIM, HID1, true><<<GB, 256, 0, stream>>>(x, Wt1, b1, normS, bufA);
    k_agg64v<true><<<AGG_B, 256, 0, stream>>>(bufA, rowptr, sortedSrc, normR, bufB);

    // layer 2: 64 -> 64, relu
    k_mgemm<HID1, HID2, false><<<GB, 256, 0, stream>>>(bufB, Wt2, b2, normS, bufA);
    k_agg64v<true><<<AGG_B, 256, 0, stream>>>(bufA, rowptr, sortedSrc, normR, bufB);

    // layer 3: 64 -> 32, no relu
    k_mgemm<HID2, OUT_DIM, false><<<GB, 256, 0, stream>>>(bufB, Wt3, b3, normS, bufA);
    k_agg32v<false><<<AGG_B, 256, 0, stream>>>(bufA, rowptr, sortedSrc, normR, bufB);

    // pooling
    k_pool<<<256, 256, 0, stream>>>(bufB, batch, out);
}